// Round 7
// baseline (581.181 us; speedup 1.0000x reference)
//
#include <hip/hip_runtime.h>
#include <hip/hip_bf16.h>

// GCN_71451075936314 on gfx950.
// R7: single change vs R6 — B-fragment pins "+v" -> "+a" (AGPR).
//     R6 evidence: (512,1) changed nothing; VGPR_Count=128 is the ARCH half
//     (occupancy 22.5% = 2 waves/SIMD = 256-reg tier, accum_offset=128).
//     "+v" pins forced all 128 B-frag regs into the 128-reg arch half ->
//     arch oversubscribed -> 61MB scratch spill on the recurrence chain.
//     "+a" moves Bi/Bh into the AGPR half (exact fit); MFMA reads B from
//     AGPR natively on gfx950 (ISA §10). Arch half now holds xf+acc+addr
//     (~100 <= 128). Zero spill expected.

#define NN     50000
#define HIDD   128
#define MAXD   16
#define NGRAPH 50
#define NCLSS  10
#define GRUH   32

typedef __attribute__((ext_vector_type(8))) short s16x8;    // 8 bf16 (4 VGPRs)
typedef __attribute__((ext_vector_type(4))) float f32x4;
typedef __hip_bfloat16 bf16;

#define MFMA16(a,b,c)  __builtin_amdgcn_mfma_f32_16x16x32_bf16((a),(b),(c),0,0,0)

__device__ __forceinline__ float bf2f(bf16 x) { return __bfloat162float(x); }
__device__ __forceinline__ bf16  f2bf(float x) { return __float2bfloat16(x); }
__device__ __forceinline__ s16x8 ldfrag(const bf16* p) { return *(const s16x8*)p; }

__device__ __forceinline__ float sigf(float x) {
  return __builtin_amdgcn_rcpf(1.0f + __expf(-x));
}
__device__ __forceinline__ float tanhf_(float x) {
  return 1.0f - 2.0f * __builtin_amdgcn_rcpf(1.0f + __expf(2.0f * x));
}

// barrier that drains LDS ops only — global loads (x prefetch) stay in flight
__device__ __forceinline__ void lgkm_barrier() {
  asm volatile("s_waitcnt lgkmcnt(0)\n\ts_barrier" ::: "memory");
}

// ---------------- prep: bf16 casts + weight transposes + bias fold ----------------
__global__ void prep_kernel(const float* __restrict__ feat, const float* __restrict__ Wih,
                            const float* __restrict__ Whh, const float* __restrict__ bih,
                            const float* __restrict__ bhh, const float* __restrict__ Wself,
                            const float* __restrict__ Wneigh, const float* __restrict__ Wgc,
                            const float* __restrict__ Wgru,
                            bf16* featB, bf16* WihB, bf16* WhhB, bf16* WsT, bf16* WnT,
                            bf16* WgT, bf16* WgruB, float* biasS) {
  const int nf = NN * HIDD;
  const int total = nf + 2 * 65536 + 3 * 16384 + 12288 + 512;
  int stride = gridDim.x * blockDim.x;
  for (int idx = blockIdx.x * blockDim.x + threadIdx.x; idx < total; idx += stride) {
    if (idx < nf) { featB[idx] = f2bf(feat[idx]); continue; }
    int j = idx - nf;
    if (j < 65536) { WihB[j] = f2bf(Wih[j]); continue; }
    j -= 65536;
    if (j < 65536) { WhhB[j] = f2bf(Whh[j]); continue; }
    j -= 65536;
    if (j < 16384) { int c = j >> 7, k = j & 127; WsT[j] = f2bf(Wself[k * HIDD + c]); continue; }
    j -= 16384;
    if (j < 16384) { int c = j >> 7, k = j & 127; WnT[j] = f2bf(Wneigh[k * HIDD + c]); continue; }
    j -= 16384;
    if (j < 16384) { int c = j >> 7, k = j & 127; WgT[j] = f2bf(Wgc[k * HIDD + c]); continue; }
    j -= 16384;
    if (j < 12288) { WgruB[j] = f2bf(Wgru[j]); continue; }
    j -= 12288;
    biasS[j] = bih[j] + bhh[j];
  }
}

// ---------------- counting sort by degree (DESCENDING): LDS hist ----------------
__global__ __launch_bounds__(256) void hist_kernel(const int* __restrict__ deg, int* hist) {
  __shared__ int lh[17];
  const int tid = threadIdx.x;
  if (tid < 17) lh[tid] = 0;
  __syncthreads();
  const int i = blockIdx.x * 256 + tid;
  if (i < NN) atomicAdd(&lh[deg[i]], 1);
  __syncthreads();
  if (tid < 17 && lh[tid]) atomicAdd(&hist[tid], lh[tid]);
}

__global__ __launch_bounds__(256) void scatter_kernel(const int* __restrict__ deg,
                                                      const int* __restrict__ hist,
                                                      int* __restrict__ resv,
                                                      int* __restrict__ perm) {
  __shared__ int lh[17], lbase[17], lpos[17];
  const int tid = threadIdx.x;
  if (tid < 17) { lh[tid] = 0; lpos[tid] = 0; }
  __syncthreads();
  const int i = blockIdx.x * 256 + tid;
  const int d = (i < NN) ? deg[i] : -1;
  if (d >= 0) atomicAdd(&lh[d], 1);
  __syncthreads();
  if (tid < 17) {
    int pre = 0;
    for (int k = tid + 1; k < 17; ++k) pre += hist[k];   // descending: larger degs first
    lbase[tid] = pre + (lh[tid] ? atomicAdd(&resv[tid], lh[tid]) : 0);
  }
  __syncthreads();
  if (d >= 0) {
    const int p = lbase[d] + atomicAdd(&lpos[d], 1);
    perm[p] = i;
  }
}

// ---------------- LSTM recurrence: 512 thr / 8 waves / 32 nodes ----------------
// Wave w owns h-cols [w*16, w*16+16) for ALL 4 gates (cols q*128 + w*16 + l15).
// Bi/Bh pinned in AGPRs (gfx950 MFMA reads B from AGPR); x A-frags register-
// prefetched one step ahead via per-lane 16B gathers. Hs xor-swizzled in LDS.
__global__ __launch_bounds__(512, 1) void lstm_kernel(const bf16* __restrict__ featB,
                                                      const bf16* __restrict__ WihB,
                                                      const bf16* __restrict__ WhhB,
                                                      const float* __restrict__ biasS,
                                                      const int* __restrict__ nbr_idx,
                                                      const int* __restrict__ deg,
                                                      const int* __restrict__ perm,
                                                      bf16* __restrict__ hTB) {
  __shared__ __align__(16) bf16 Hs[32 * 128];   // h tile, xor-swizzled, 8KB
  __shared__ int nbr_s[16 * 32];                // [t][row] transposed: conflict-free reads
  __shared__ int nodes_s[32];
  __shared__ int degs_s[32];

  const int tid = threadIdx.x;
  const int lane = tid & 63, w = tid >> 6;      // w = h-col block
  const int l15 = lane & 15, quad = lane >> 4;
  const int base = blockIdx.x * 32;
  const int colw = w * 16 + l15;                // this thread's h-col

  if (tid < 32) {
    const int gi = base + tid;
    const int nd = (gi < NN) ? perm[gi] : -1;
    nodes_s[tid] = nd;
    degs_s[tid] = (nd >= 0) ? deg[nd] : 0;
  }
  __syncthreads();
  for (int e = tid; e < 16 * 32; e += 512) {
    const int row = e & 31, t = e >> 5;
    const int nd = nodes_s[row];
    nbr_s[t * 32 + row] = (nd >= 0) ? nbr_idx[nd * MAXD + t] : 0;
  }
  for (int e = tid; e < 32 * 64; e += 512) ((unsigned int*)Hs)[e] = 0u;

  // B fragments, pinned in AGPRs: frees the arch-VGPR half for xf/acc/addr
  s16x8 Bi[4][4], Bh[4][4];
#pragma unroll
  for (int q = 0; q < 4; ++q) {
    const int col = q * 128 + colw;
#pragma unroll
    for (int kt = 0; kt < 4; ++kt) {
      Bi[q][kt] = ldfrag(WihB + col * HIDD + kt * 32 + quad * 8);
      Bh[q][kt] = ldfrag(WhhB + col * HIDD + kt * 32 + quad * 8);
      asm volatile("" : "+a"(Bi[q][kt]));
      asm volatile("" : "+a"(Bh[q][kt]));
    }
  }
  float biasv[4];
#pragma unroll
  for (int q = 0; q < 4; ++q) biasv[q] = biasS[q * 128 + colw];

  __syncthreads();                              // nbr_s, degs_s, Hs-zero visible
  const int maxdeg = degs_s[0];                 // descending sort -> first is block max

  int mydeg[2][4];
#pragma unroll
  for (int rt = 0; rt < 2; ++rt)
#pragma unroll
    for (int rr = 0; rr < 4; ++rr) mydeg[rt][rr] = degs_s[rt * 16 + quad * 4 + rr];

  // prefetch x A-frags for t=0: lane -> row rt*16+l15, k = kt*32+quad*8
  s16x8 xf[2][4];
#pragma unroll
  for (int rt = 0; rt < 2; ++rt) {
    const int nb0 = nbr_s[0 * 32 + rt * 16 + l15];
#pragma unroll
    for (int kt = 0; kt < 4; ++kt)
      xf[rt][kt] = ldfrag(featB + (size_t)nb0 * HIDD + kt * 32 + quad * 8);
  }

  float cst[2][4] = {{0.f, 0.f, 0.f, 0.f}, {0.f, 0.f, 0.f, 0.f}};

  for (int t = 0; t < maxdeg; ++t) {
    f32x4 acc[2][4];
#pragma unroll
    for (int rt = 0; rt < 2; ++rt)
#pragma unroll
      for (int q = 0; q < 4; ++q) acc[rt][q] = (f32x4){0.f, 0.f, 0.f, 0.f};

    // x-part: gates += x_t @ Wih^T
#pragma unroll
    for (int rt = 0; rt < 2; ++rt)
#pragma unroll
      for (int kt = 0; kt < 4; ++kt)
#pragma unroll
        for (int q = 0; q < 4; ++q)
          acc[rt][q] = MFMA16(xf[rt][kt], Bi[q][kt], acc[rt][q]);

    // prefetch x for t+1 (latency covered by h-part + elementwise)
    if (t + 1 < maxdeg) {
#pragma unroll
      for (int rt = 0; rt < 2; ++rt) {
        const int nb1 = nbr_s[(t + 1) * 32 + rt * 16 + l15];
#pragma unroll
        for (int kt = 0; kt < 4; ++kt)
          xf[rt][kt] = ldfrag(featB + (size_t)nb1 * HIDD + kt * 32 + quad * 8);
      }
    }

    // h-part: gates += h_{t-1} @ Whh^T   (skip at t=0: h0 = 0)
    if (t > 0) {
#pragma unroll
      for (int rt = 0; rt < 2; ++rt)
#pragma unroll
        for (int kt = 0; kt < 4; ++kt) {
          const int m = rt * 16 + l15;
          const int k = kt * 32 + quad * 8;
          const s16x8 ah = ldfrag(Hs + m * 128 + (k ^ (l15 * 8)));
#pragma unroll
          for (int q = 0; q < 4; ++q)
            acc[rt][q] = MFMA16(ah, Bh[q][kt], acc[rt][q]);
        }
    }
    lgkm_barrier();   // all waves' Hs reads complete before overwrite

    // elementwise LSTM cell (rows rt*16 + quad*4 + rr, col colw)
#pragma unroll
    for (int rt = 0; rt < 2; ++rt)
#pragma unroll
      for (int rr = 0; rr < 4; ++rr) {
        const int row = rt * 16 + quad * 4 + rr;
        const float g_i = acc[rt][0][rr] + biasv[0];
        const float g_f = acc[rt][1][rr] + biasv[1];
        const float g_g = acc[rt][2][rr] + biasv[2];
        const float g_o = acc[rt][3][rr] + biasv[3];
        const float iv = sigf(g_i), fv = sigf(g_f);
        const float gv = tanhf_(g_g), ov = sigf(g_o);
        const float cn = fv * cst[rt][rr] + iv * gv;
        const float hn = ov * tanhf_(cn);
        if (t < mydeg[rt][rr]) {
          cst[rt][rr] = cn;
          Hs[row * 128 + (colw ^ ((row & 15) * 8))] = f2bf(hn);
        }
      }
    lgkm_barrier();   // Hs writes visible for next step's h-part
  }

  // epilogue: Hs (swizzled) -> hTB
  for (int e = tid; e < 32 * 16; e += 512) {
    const int row = e >> 4, j = e & 15;
    const int nd = nodes_s[row];
    if (nd >= 0) {
      const s16x8 v = ldfrag(Hs + row * 128 + ((j * 8) ^ ((row & 15) * 8)));
      *(s16x8*)(hTB + (size_t)nd * HIDD + j * 8) = v;
    }
  }
}

// ------- SAGE: h1n = relu(feat@W_self + hT@W_neigh + b) * rsqrt(deg) -------
__global__ __launch_bounds__(256) void sage_kernel(const bf16* __restrict__ featB,
                                                   const bf16* __restrict__ hTB,
                                                   const bf16* __restrict__ WsT,
                                                   const bf16* __restrict__ WnT,
                                                   const float* __restrict__ b_sage,
                                                   const int* __restrict__ deg,
                                                   bf16* __restrict__ h1n) {
  const int lane = threadIdx.x & 63, wave = threadIdx.x >> 6;
  const int l15 = lane & 15, quad = lane >> 4;
  const int nb = blockIdx.x * 64 + wave * 16;
  int arow = nb + l15; if (arow >= NN) arow = NN - 1;
  s16x8 Fa[4], Ha[4];
#pragma unroll
  for (int kt = 0; kt < 4; ++kt) {
    Fa[kt] = ldfrag(featB + (size_t)arow * HIDD + kt * 32 + quad * 8);
    Ha[kt] = ldfrag(hTB + (size_t)arow * HIDD + kt * 32 + quad * 8);
  }
  int nodes[4]; float nrm[4];
#pragma unroll
  for (int r = 0; r < 4; ++r) {
    const int nd = nb + quad * 4 + r;
    nodes[r] = nd;
    nrm[r] = rsqrtf((float)deg[(nd < NN) ? nd : (NN - 1)]);
  }
  for (int ct = 0; ct < 8; ++ct) {
    const int col = ct * 16 + l15;
    f32x4 acc = {0.f, 0.f, 0.f, 0.f};
#pragma unroll
    for (int kt = 0; kt < 4; ++kt) {
      acc = MFMA16(Fa[kt], ldfrag(WsT + col * HIDD + kt * 32 + quad * 8), acc);
      acc = MFMA16(Ha[kt], ldfrag(WnT + col * HIDD + kt * 32 + quad * 8), acc);
    }
    const float bb = b_sage[col];
#pragma unroll
    for (int r = 0; r < 4; ++r)
      if (nodes[r] < NN) {
        const float v = fmaxf(acc[r] + bb, 0.f) * nrm[r];
        h1n[(size_t)nodes[r] * HIDD + col] = f2bf(v);
      }
  }
}

// ------- GraphConv aggregate: agg[n] = rsqrt(deg[n]) * sum_{t<deg} h1n[nbr[n,t]] -------
__global__ __launch_bounds__(256) void agg_kernel(const bf16* __restrict__ h1n,
                                                  const int* __restrict__ nbr_idx,
                                                  const int* __restrict__ deg,
                                                  bf16* __restrict__ aggB) {
  const int wave = threadIdx.x >> 6, lane = threadIdx.x & 63;
  const int node = blockIdx.x * 4 + wave;
  if (node >= NN) return;
  const int d = deg[node];
  const int idx_l = nbr_idx[node * MAXD + (lane & 15)];   // coalesced, broadcast via shfl
  const int c = lane * 2;
  float a0 = 0.f, a1 = 0.f;
  for (int t = 0; t < d; ++t) {
    const int nbr = __shfl(idx_l, t, 64);
    const __hip_bfloat162 v = *(const __hip_bfloat162*)(h1n + (size_t)nbr * HIDD + c);
    a0 += __bfloat162float(v.x);
    a1 += __bfloat162float(v.y);
  }
  const float nm = rsqrtf((float)d);
  aggB[(size_t)node * HIDD + c]     = f2bf(a0 * nm);
  aggB[(size_t)node * HIDD + c + 1] = f2bf(a1 * nm);
}

// ------- GraphConv GEMM: h2 = relu(agg @ W_gc + b_gc) -------
__global__ __launch_bounds__(256) void gc_gemm_kernel(const bf16* __restrict__ aggB,
                                                      const bf16* __restrict__ WgT,
                                                      const float* __restrict__ b_gc,
                                                      bf16* __restrict__ h2B) {
  const int lane = threadIdx.x & 63, wave = threadIdx.x >> 6;
  const int l15 = lane & 15, quad = lane >> 4;
  const int nb = blockIdx.x * 64 + wave * 16;
  int arow = nb + l15; if (arow >= NN) arow = NN - 1;
  s16x8 A[4];
#pragma unroll
  for (int kt = 0; kt < 4; ++kt) A[kt] = ldfrag(aggB + (size_t)arow * HIDD + kt * 32 + quad * 8);
  for (int ct = 0; ct < 8; ++ct) {
    const int col = ct * 16 + l15;
    f32x4 acc = {0.f, 0.f, 0.f, 0.f};
#pragma unroll
    for (int kt = 0; kt < 4; ++kt)
      acc = MFMA16(A[kt], ldfrag(WgT + col * HIDD + kt * 32 + quad * 8), acc);
    const float bb = b_gc[col];
#pragma unroll
    for (int r = 0; r < 4; ++r) {
      const int node = nb + quad * 4 + r;
      if (node < NN) h2B[(size_t)node * HIDD + col] = f2bf(fmaxf(acc[r] + bb, 0.f));
    }
  }
}

// ------- GRU (seq_len=1, h0=0): out = (1-z)*tanh(xn + r*bn) -------
__global__ __launch_bounds__(256) void gru_kernel(const bf16* __restrict__ h2B,
                                                  const bf16* __restrict__ WgruB,
                                                  const float* __restrict__ bih,
                                                  const float* __restrict__ bhh,
                                                  float* __restrict__ gout) {
  const int lane = threadIdx.x & 63, wave = threadIdx.x >> 6;
  const int l15 = lane & 15, quad = lane >> 4;
  const int nb = blockIdx.x * 64 + wave * 16;
  int arow = nb + l15; if (arow >= NN) arow = NN - 1;
  s16x8 A[4];
#pragma unroll
  for (int kt = 0; kt < 4; ++kt) A[kt] = ldfrag(h2B + (size_t)arow * HIDD + kt * 32 + quad * 8);
  f32x4 acc[6];
#pragma unroll
  for (int ct = 0; ct < 6; ++ct) {
    f32x4 a = {0.f, 0.f, 0.f, 0.f};
#pragma unroll
    for (int kt = 0; kt < 4; ++kt)
      a = MFMA16(A[kt], ldfrag(WgruB + (ct * 16 + l15) * HIDD + kt * 32 + quad * 8), a);
    acc[ct] = a;
  }
#pragma unroll
  for (int u = 0; u < 2; ++u) {
    const int cu = 16 * u + l15;
    const float br = bih[cu] + bhh[cu];
    const float bz = bih[32 + cu] + bhh[32 + cu];
    const float bni = bih[64 + cu];
    const float bnh = bhh[64 + cu];
#pragma unroll
    for (int r = 0; r < 4; ++r) {
      const int node = nb + quad * 4 + r;
      if (node < NN) {
        const float rv = sigf(acc[u][r] + br);
        const float zv = sigf(acc[2 + u][r] + bz);
        const float nv = tanhf_(acc[4 + u][r] + bni + rv * bnh);
        gout[(size_t)node * GRUH + cu] = (1.f - zv) * nv;
      }
    }
  }
}

// ------- two-phase per-graph mean pool + classifier -------
#define POOL_CHUNK 512
__global__ __launch_bounds__(256) void pool_partial_kernel(const float* __restrict__ gout,
                                                           const int* __restrict__ gids,
                                                           float* __restrict__ sums,
                                                           float* __restrict__ cnts) {
  __shared__ float ls[NGRAPH * GRUH];
  __shared__ float lc[NGRAPH];
  const int tid = threadIdx.x;
  for (int i = tid; i < NGRAPH * GRUH; i += 256) ls[i] = 0.f;
  if (tid < NGRAPH) lc[tid] = 0.f;
  __syncthreads();

  const int wave = tid >> 6, lane = tid & 63;
  const int c = lane & 31, half = lane >> 5;
  const int base = blockIdx.x * POOL_CHUNK + wave * (POOL_CHUNK / 8);

  float accv = 0.f, ccnt = 0.f;
  int curg = -1;
  for (int it = 0; it < POOL_CHUNK / 16; ++it) {
    const int n = base + it * 2 + half;
    if (n < NN) {
      const int g = gids[n];
      const float v = gout[(size_t)n * GRUH + c];
      if (g != curg) {
        if (curg >= 0) {
          atomicAdd(&ls[curg * GRUH + c], accv);
          if (c == 0) atomicAdd(&lc[curg], ccnt);
        }
        curg = g; accv = 0.f; ccnt = 0.f;
      }
      accv += v; ccnt += 1.f;
    }
  }
  if (curg >= 0) {
    atomicAdd(&ls[curg * GRUH + c], accv);
    if (c == 0) atomicAdd(&lc[curg], ccnt);
  }
  __syncthreads();
  for (int i = tid; i < NGRAPH * GRUH; i += 256)
    if (ls[i] != 0.f) atomicAdd(&sums[i], ls[i]);
  if (tid < NGRAPH && lc[tid] != 0.f) atomicAdd(&cnts[tid], lc[tid]);
}

__global__ __launch_bounds__(256) void pool_final_kernel(const float* __restrict__ sums,
                                                         const float* __restrict__ cnts,
                                                         const float* __restrict__ Wcls,
                                                         const float* __restrict__ bcls,
                                                         float* __restrict__ out) {
  const int idx = blockIdx.x * blockDim.x + threadIdx.x;
  if (idx >= NGRAPH * NCLSS) return;
  const int g = idx / NCLSS, k = idx % NCLSS;
  const float inv = 1.0f / cnts[g];
  float acc = bcls[k];
#pragma unroll
  for (int cc = 0; cc < GRUH; ++cc)
    acc += sums[g * GRUH + cc] * inv * Wcls[cc * NCLSS + k];
  out[idx] = acc;
}

extern "C" void kernel_launch(void* const* d_in, const int* in_sizes, int n_in,
                              void* d_out, int out_size, void* d_ws, size_t ws_size,
                              hipStream_t stream) {
  const float* feature  = (const float*)d_in[0];
  const int*   nbr_idx  = (const int*)d_in[1];
  const int*   deg      = (const int*)d_in[2];
  const int*   gids     = (const int*)d_in[3];
  const float* lstm_Wih = (const float*)d_in[4];
  const float* lstm_Whh = (const float*)d_in[5];
  const float* lstm_bih = (const float*)d_in[6];
  const float* lstm_bhh = (const float*)d_in[7];
  const float* W_self   = (const float*)d_in[8];
  const float* W_neigh  = (const float*)d_in[9];
  const float* b_sage   = (const float*)d_in[10];
  const float* W_gc     = (const float*)d_in[11];
  const float* b_gc     = (const float*)d_in[12];
  const float* Wih_gru  = (const float*)d_in[13];
  const float* bih_gru  = (const float*)d_in[14];
  const float* bhh_gru  = (const float*)d_in[15];
  const float* W_cls    = (const float*)d_in[16];
  const float* b_cls    = (const float*)d_in[17];

  // workspace: peak ~66 MB
  char* ws = (char*)d_ws;
  bf16*  featB = (bf16*)(ws + 0);           // [NN,128] 12.8MB (dead after sage)
  bf16*  hTB   = (bf16*)(ws + 12800000);    // [NN,128] (dead after sage)
  bf16*  h1nB  = (bf16*)(ws + 25600000);    // [NN,128] (dead after agg)
  bf16*  aggB  = (bf16*)(ws + 38400000);    // [NN,128] (dead after gc)
  bf16*  h2B   = (bf16*)(ws + 51200000);    // [NN,128]
  float* gout  = (float*)(ws + 12800000);   // alias hTB (dead after sage)
  const size_t wo = 64000000;
  bf16*  WihB  = (bf16*)(ws + wo);
  bf16*  WhhB  = (bf16*)(ws + wo + 131072);
  bf16*  WsT   = (bf16*)(ws + wo + 262144);
  bf16*  WnT   = (bf16*)(ws + wo + 294912);
  bf16*  WgT   = (bf16*)(ws + wo + 327680);
  bf16*  WgruB = (bf16*)(ws + wo + 360448);
  float* biasS = (float*)(ws + wo + 385024);
  int*   perm  = (int*)(ws + 65000000);
  int*   hist  = (int*)(ws + 65400000);     // [17]
  int*   resv  = hist + 17;                 // [17]
  float* psums = (float*)(ws + 65401216);   // [50][32]
  float* pcnts = psums + NGRAPH * GRUH;     // [50]

  prep_kernel<<<3072, 256, 0, stream>>>(feature, lstm_Wih, lstm_Whh, lstm_bih, lstm_bhh,
                                        W_self, W_neigh, W_gc, Wih_gru,
                                        featB, WihB, WhhB, WsT, WnT, WgT, WgruB, biasS);
  hipMemsetAsync(hist, 0, 34 * sizeof(int), stream);
  hipMemsetAsync(psums, 0, (NGRAPH * GRUH + NGRAPH) * sizeof(float), stream);
  hist_kernel<<<196, 256, 0, stream>>>(deg, hist);
  scatter_kernel<<<196, 256, 0, stream>>>(deg, hist, resv, perm);
  lstm_kernel<<<1563, 512, 0, stream>>>(featB, WihB, WhhB, biasS, nbr_idx, deg, perm, hTB);
  sage_kernel<<<782, 256, 0, stream>>>(featB, hTB, WsT, WnT, b_sage, deg, h1nB);
  agg_kernel<<<12500, 256, 0, stream>>>(h1nB, nbr_idx, deg, aggB);
  gc_gemm_kernel<<<782, 256, 0, stream>>>(aggB, WgT, b_gc, h2B);
  gru_kernel<<<782, 256, 0, stream>>>(h2B, WgruB, bih_gru, bhh_gru, gout);
  pool_partial_kernel<<<(NN + POOL_CHUNK - 1) / POOL_CHUNK, 256, 0, stream>>>(gout, gids, psums, pcnts);
  pool_final_kernel<<<2, 256, 0, stream>>>(psums, pcnts, W_cls, b_cls, (float*)d_out);
}

// Round 8
// 447.936 us; speedup vs baseline: 1.2975x; 1.2975x over previous
//
#include <hip/hip_runtime.h>
#include <hip/hip_bf16.h>

// GCN_71451075936314 on gfx950.
// R8: lstm register-demand restructure. R5-R7 proved full B-residency is
//     impossible: Wih+Whh = 256KB / 512thr = 128 VGPR/thread + ~100 working
//     regs > the 128-arch cap the allocator enforces -> 61-98MB scratch spill
//     on the serial chain ("+a" pins made it WORSE: accvgpr_read copies).
//     Fix: Wih -> LDS (128KB, chunk-XOR-swizzled, ds_read_b128 B-frags);
//     only Whh pinned (16 frags = 64 VGPR); x A-frags staged per-step into
//     double-buffered 272B-padded Xs in LDS (1 global b128/thread/step).
//     Arch demand ~95-125 <= 128 -> no spill. LDS/step ~272KB ~ 2100cyc.

#define NN     50000
#define HIDD   128
#define MAXD   16
#define NGRAPH 50
#define NCLSS  10
#define GRUH   32

typedef __attribute__((ext_vector_type(8))) short s16x8;    // 8 bf16 (4 VGPRs)
typedef __attribute__((ext_vector_type(4))) float f32x4;
typedef __hip_bfloat16 bf16;

#define MFMA16(a,b,c)  __builtin_amdgcn_mfma_f32_16x16x32_bf16((a),(b),(c),0,0,0)

__device__ __forceinline__ float bf2f(bf16 x) { return __bfloat162float(x); }
__device__ __forceinline__ bf16  f2bf(float x) { return __float2bfloat16(x); }
__device__ __forceinline__ s16x8 ldfrag(const bf16* p) { return *(const s16x8*)p; }

__device__ __forceinline__ float sigf(float x) {
  return __builtin_amdgcn_rcpf(1.0f + __expf(-x));
}
__device__ __forceinline__ float tanhf_(float x) {
  return 1.0f - 2.0f * __builtin_amdgcn_rcpf(1.0f + __expf(2.0f * x));
}

// barrier that drains LDS ops only — global loads stay in flight
__device__ __forceinline__ void lgkm_barrier() {
  asm volatile("s_waitcnt lgkmcnt(0)\n\ts_barrier" ::: "memory");
}

// ---------------- prep: bf16 casts + weight transposes + bias fold ----------------
__global__ void prep_kernel(const float* __restrict__ feat, const float* __restrict__ Wih,
                            const float* __restrict__ Whh, const float* __restrict__ bih,
                            const float* __restrict__ bhh, const float* __restrict__ Wself,
                            const float* __restrict__ Wneigh, const float* __restrict__ Wgc,
                            const float* __restrict__ Wgru,
                            bf16* featB, bf16* WihB, bf16* WhhB, bf16* WsT, bf16* WnT,
                            bf16* WgT, bf16* WgruB, float* biasS) {
  const int nf = NN * HIDD;
  const int total = nf + 2 * 65536 + 3 * 16384 + 12288 + 512;
  int stride = gridDim.x * blockDim.x;
  for (int idx = blockIdx.x * blockDim.x + threadIdx.x; idx < total; idx += stride) {
    if (idx < nf) { featB[idx] = f2bf(feat[idx]); continue; }
    int j = idx - nf;
    if (j < 65536) { WihB[j] = f2bf(Wih[j]); continue; }
    j -= 65536;
    if (j < 65536) { WhhB[j] = f2bf(Whh[j]); continue; }
    j -= 65536;
    if (j < 16384) { int c = j >> 7, k = j & 127; WsT[j] = f2bf(Wself[k * HIDD + c]); continue; }
    j -= 16384;
    if (j < 16384) { int c = j >> 7, k = j & 127; WnT[j] = f2bf(Wneigh[k * HIDD + c]); continue; }
    j -= 16384;
    if (j < 16384) { int c = j >> 7, k = j & 127; WgT[j] = f2bf(Wgc[k * HIDD + c]); continue; }
    j -= 16384;
    if (j < 12288) { WgruB[j] = f2bf(Wgru[j]); continue; }
    j -= 12288;
    biasS[j] = bih[j] + bhh[j];
  }
}

// ---------------- counting sort by degree (DESCENDING): LDS hist ----------------
__global__ __launch_bounds__(256) void hist_kernel(const int* __restrict__ deg, int* hist) {
  __shared__ int lh[17];
  const int tid = threadIdx.x;
  if (tid < 17) lh[tid] = 0;
  __syncthreads();
  const int i = blockIdx.x * 256 + tid;
  if (i < NN) atomicAdd(&lh[deg[i]], 1);
  __syncthreads();
  if (tid < 17 && lh[tid]) atomicAdd(&hist[tid], lh[tid]);
}

__global__ __launch_bounds__(256) void scatter_kernel(const int* __restrict__ deg,
                                                      const int* __restrict__ hist,
                                                      int* __restrict__ resv,
                                                      int* __restrict__ perm) {
  __shared__ int lh[17], lbase[17], lpos[17];
  const int tid = threadIdx.x;
  if (tid < 17) { lh[tid] = 0; lpos[tid] = 0; }
  __syncthreads();
  const int i = blockIdx.x * 256 + tid;
  const int d = (i < NN) ? deg[i] : -1;
  if (d >= 0) atomicAdd(&lh[d], 1);
  __syncthreads();
  if (tid < 17) {
    int pre = 0;
    for (int k = tid + 1; k < 17; ++k) pre += hist[k];   // descending: larger degs first
    lbase[tid] = pre + (lh[tid] ? atomicAdd(&resv[tid], lh[tid]) : 0);
  }
  __syncthreads();
  if (d >= 0) {
    const int p = lbase[d] + atomicAdd(&lpos[d], 1);
    perm[p] = i;
  }
}

// ---------------- LSTM recurrence: 512 thr / 8 waves / 32 nodes ----------------
// Wave w owns h-cols [w*16, w*16+16) for ALL 4 gates. Whh frags pinned (64 VGPR);
// Wih in LDS (chunk-xor swizzle); x rows staged per-step into padded Xs dbuf.
__global__ __launch_bounds__(512, 1) void lstm_kernel(const bf16* __restrict__ featB,
                                                      const bf16* __restrict__ WihB,
                                                      const bf16* __restrict__ WhhB,
                                                      const float* __restrict__ biasS,
                                                      const int* __restrict__ nbr_idx,
                                                      const int* __restrict__ deg,
                                                      const int* __restrict__ perm,
                                                      bf16* __restrict__ hTB) {
  __shared__ __align__(16) bf16 WiS[512 * 128];   // Wih, chunk-xor-swizzled, 128KB
  __shared__ __align__(16) bf16 Xs[2][32 * 136];  // x rows, 272B-padded, dbuf, 17KB
  __shared__ __align__(16) bf16 Hs[32 * 128];     // h tile, xor-swizzled, 8KB
  __shared__ int nbr_s[16 * 32];                  // [t][row]
  __shared__ int nodes_s[32];
  __shared__ int degs_s[32];

  const int tid = threadIdx.x;
  const int lane = tid & 63, w = tid >> 6;        // w = h-col block
  const int l15 = lane & 15, quad = lane >> 4;
  const int base = blockIdx.x * 32;
  const int colw = w * 16 + l15;                  // this thread's h-col

  if (tid < 32) {
    const int gi = base + tid;
    const int nd = (gi < NN) ? perm[gi] : -1;
    nodes_s[tid] = nd;
    degs_s[tid] = (nd >= 0) ? deg[nd] : 0;
  }
  __syncthreads();
  // neighbor table + Hs zero + Wih -> LDS (swizzled: chunk j of col c at j^(c&15))
  for (int e = tid; e < 16 * 32; e += 512) {
    const int row = e & 31, t = e >> 5;
    const int nd = nodes_s[row];
    nbr_s[t * 32 + row] = (nd >= 0) ? nbr_idx[nd * MAXD + t] : 0;
  }
  for (int e = tid; e < 32 * 64; e += 512) ((unsigned int*)Hs)[e] = 0u;
  {
    const int c = tid;                            // one col per thread
#pragma unroll
    for (int j = 0; j < 16; ++j)
      *(s16x8*)(WiS + c * 128 + ((j ^ (c & 15)) * 8)) = ldfrag(WihB + c * HIDD + j * 8);
  }

  // Whh fragments, pinned (64 VGPR — fits alongside working set)
  s16x8 Bh[4][4];
#pragma unroll
  for (int q = 0; q < 4; ++q)
#pragma unroll
    for (int kt = 0; kt < 4; ++kt) {
      Bh[q][kt] = ldfrag(WhhB + (q * 128 + colw) * HIDD + kt * 32 + quad * 8);
      asm volatile("" : "+v"(Bh[q][kt]));
    }
  float biasv[4];
#pragma unroll
  for (int q = 0; q < 4; ++q) biasv[q] = biasS[q * 128 + colw];

  __syncthreads();                                // WiS, nbr_s, Hs visible
  const int maxdeg = degs_s[0];                   // descending sort -> block max

  int mydeg[2][4];
#pragma unroll
  for (int rt = 0; rt < 2; ++rt)
#pragma unroll
    for (int rr = 0; rr < 4; ++rr) mydeg[rt][rr] = degs_s[rt * 16 + quad * 4 + rr];

  // stage x for t=0: thread -> row tid>>4, 16B chunk tid&15
  const int srow = tid >> 4, schk = tid & 15;
  {
    const int nb0 = nbr_s[0 * 32 + srow];
    *(s16x8*)(&Xs[0][srow * 136 + schk * 8]) = ldfrag(featB + (size_t)nb0 * HIDD + schk * 8);
  }
  float cst[2][4] = {{0.f, 0.f, 0.f, 0.f}, {0.f, 0.f, 0.f, 0.f}};
  lgkm_barrier();                                 // Xs[0] visible

  for (int t = 0; t < maxdeg; ++t) {
    // issue next step's x global load early (latency covered by GEMMs)
    s16x8 xstage;
    const bool do_stage = (t + 1 < maxdeg);
    if (do_stage) {
      const int nb1 = nbr_s[(t + 1) * 32 + srow];
      xstage = ldfrag(featB + (size_t)nb1 * HIDD + schk * 8);
    }

    f32x4 acc[2][4];
#pragma unroll
    for (int rt = 0; rt < 2; ++rt)
#pragma unroll
      for (int q = 0; q < 4; ++q) acc[rt][q] = (f32x4){0.f, 0.f, 0.f, 0.f};

    // x-part: gates += x_t @ Wih^T  (A from Xs, B from WiS — both LDS)
    const bf16* Xc = &Xs[t & 1][0];
#pragma unroll
    for (int kt = 0; kt < 4; ++kt) {
      s16x8 ax0 = ldfrag(Xc + (0 * 16 + l15) * 136 + (kt * 4 + quad) * 8);
      s16x8 ax1 = ldfrag(Xc + (1 * 16 + l15) * 136 + (kt * 4 + quad) * 8);
#pragma unroll
      for (int q = 0; q < 4; ++q) {
        const int col = q * 128 + colw;
        const s16x8 bi = ldfrag(WiS + col * 128 + (((kt * 4 + quad) ^ (col & 15)) * 8));
        acc[0][q] = MFMA16(ax0, bi, acc[0][q]);
        acc[1][q] = MFMA16(ax1, bi, acc[1][q]);
      }
    }

    // h-part: gates += h_{t-1} @ Whh^T   (skip at t=0: h0 = 0)
    if (t > 0) {
#pragma unroll
      for (int rt = 0; rt < 2; ++rt)
#pragma unroll
        for (int kt = 0; kt < 4; ++kt) {
          const int m = rt * 16 + l15;
          const int k = kt * 32 + quad * 8;
          const s16x8 ah = ldfrag(Hs + m * 128 + (k ^ (l15 * 8)));
#pragma unroll
          for (int q = 0; q < 4; ++q)
            acc[rt][q] = MFMA16(ah, Bh[q][kt], acc[rt][q]);
        }
    }
    lgkm_barrier();   // all waves' Hs/Xs reads complete before overwrite

    // stage next x into the other buffer (vmcnt auto-waited before ds_write)
    if (do_stage)
      *(s16x8*)(&Xs[(t + 1) & 1][srow * 136 + schk * 8]) = xstage;

    // elementwise LSTM cell (rows rt*16 + quad*4 + rr, col colw)
#pragma unroll
    for (int rt = 0; rt < 2; ++rt)
#pragma unroll
      for (int rr = 0; rr < 4; ++rr) {
        const int row = rt * 16 + quad * 4 + rr;
        const float g_i = acc[rt][0][rr] + biasv[0];
        const float g_f = acc[rt][1][rr] + biasv[1];
        const float g_g = acc[rt][2][rr] + biasv[2];
        const float g_o = acc[rt][3][rr] + biasv[3];
        const float iv = sigf(g_i), fv = sigf(g_f);
        const float gv = tanhf_(g_g), ov = sigf(g_o);
        const float cn = fv * cst[rt][rr] + iv * gv;
        const float hn = ov * tanhf_(cn);
        if (t < mydeg[rt][rr]) {
          cst[rt][rr] = cn;
          Hs[row * 128 + (colw ^ ((row & 15) * 8))] = f2bf(hn);
        }
      }
    lgkm_barrier();   // Hs + Xs writes visible for next step
  }

  // epilogue: Hs (swizzled) -> hTB
  for (int e = tid; e < 32 * 16; e += 512) {
    const int row = e >> 4, j = e & 15;
    const int nd = nodes_s[row];
    if (nd >= 0) {
      const s16x8 v = ldfrag(Hs + row * 128 + ((j * 8) ^ ((row & 15) * 8)));
      *(s16x8*)(hTB + (size_t)nd * HIDD + j * 8) = v;
    }
  }
}

// ------- SAGE: h1n = relu(feat@W_self + hT@W_neigh + b) * rsqrt(deg) -------
__global__ __launch_bounds__(256) void sage_kernel(const bf16* __restrict__ featB,
                                                   const bf16* __restrict__ hTB,
                                                   const bf16* __restrict__ WsT,
                                                   const bf16* __restrict__ WnT,
                                                   const float* __restrict__ b_sage,
                                                   const int* __restrict__ deg,
                                                   bf16* __restrict__ h1n) {
  const int lane = threadIdx.x & 63, wave = threadIdx.x >> 6;
  const int l15 = lane & 15, quad = lane >> 4;
  const int nb = blockIdx.x * 64 + wave * 16;
  int arow = nb + l15; if (arow >= NN) arow = NN - 1;
  s16x8 Fa[4], Ha[4];
#pragma unroll
  for (int kt = 0; kt < 4; ++kt) {
    Fa[kt] = ldfrag(featB + (size_t)arow * HIDD + kt * 32 + quad * 8);
    Ha[kt] = ldfrag(hTB + (size_t)arow * HIDD + kt * 32 + quad * 8);
  }
  int nodes[4]; float nrm[4];
#pragma unroll
  for (int r = 0; r < 4; ++r) {
    const int nd = nb + quad * 4 + r;
    nodes[r] = nd;
    nrm[r] = rsqrtf((float)deg[(nd < NN) ? nd : (NN - 1)]);
  }
  for (int ct = 0; ct < 8; ++ct) {
    const int col = ct * 16 + l15;
    f32x4 acc = {0.f, 0.f, 0.f, 0.f};
#pragma unroll
    for (int kt = 0; kt < 4; ++kt) {
      acc = MFMA16(Fa[kt], ldfrag(WsT + col * HIDD + kt * 32 + quad * 8), acc);
      acc = MFMA16(Ha[kt], ldfrag(WnT + col * HIDD + kt * 32 + quad * 8), acc);
    }
    const float bb = b_sage[col];
#pragma unroll
    for (int r = 0; r < 4; ++r)
      if (nodes[r] < NN) {
        const float v = fmaxf(acc[r] + bb, 0.f) * nrm[r];
        h1n[(size_t)nodes[r] * HIDD + col] = f2bf(v);
      }
  }
}

// ------- GraphConv aggregate: agg[n] = rsqrt(deg[n]) * sum_{t<deg} h1n[nbr[n,t]] -------
__global__ __launch_bounds__(256) void agg_kernel(const bf16* __restrict__ h1n,
                                                  const int* __restrict__ nbr_idx,
                                                  const int* __restrict__ deg,
                                                  bf16* __restrict__ aggB) {
  const int wave = threadIdx.x >> 6, lane = threadIdx.x & 63;
  const int node = blockIdx.x * 4 + wave;
  if (node >= NN) return;
  const int d = deg[node];
  const int idx_l = nbr_idx[node * MAXD + (lane & 15)];   // coalesced, broadcast via shfl
  const int c = lane * 2;
  float a0 = 0.f, a1 = 0.f;
  for (int t = 0; t < d; ++t) {
    const int nbr = __shfl(idx_l, t, 64);
    const __hip_bfloat162 v = *(const __hip_bfloat162*)(h1n + (size_t)nbr * HIDD + c);
    a0 += __bfloat162float(v.x);
    a1 += __bfloat162float(v.y);
  }
  const float nm = rsqrtf((float)d);
  aggB[(size_t)node * HIDD + c]     = f2bf(a0 * nm);
  aggB[(size_t)node * HIDD + c + 1] = f2bf(a1 * nm);
}

// ------- GraphConv GEMM: h2 = relu(agg @ W_gc + b_gc) -------
__global__ __launch_bounds__(256) void gc_gemm_kernel(const bf16* __restrict__ aggB,
                                                      const bf16* __restrict__ WgT,
                                                      const float* __restrict__ b_gc,
                                                      bf16* __restrict__ h2B) {
  const int lane = threadIdx.x & 63, wave = threadIdx.x >> 6;
  const int l15 = lane & 15, quad = lane >> 4;
  const int nb = blockIdx.x * 64 + wave * 16;
  int arow = nb + l15; if (arow >= NN) arow = NN - 1;
  s16x8 A[4];
#pragma unroll
  for (int kt = 0; kt < 4; ++kt) A[kt] = ldfrag(aggB + (size_t)arow * HIDD + kt * 32 + quad * 8);
  for (int ct = 0; ct < 8; ++ct) {
    const int col = ct * 16 + l15;
    f32x4 acc = {0.f, 0.f, 0.f, 0.f};
#pragma unroll
    for (int kt = 0; kt < 4; ++kt)
      acc = MFMA16(A[kt], ldfrag(WgT + col * HIDD + kt * 32 + quad * 8), acc);
    const float bb = b_gc[col];
#pragma unroll
    for (int r = 0; r < 4; ++r) {
      const int node = nb + quad * 4 + r;
      if (node < NN) h2B[(size_t)node * HIDD + col] = f2bf(fmaxf(acc[r] + bb, 0.f));
    }
  }
}

// ------- GRU (seq_len=1, h0=0): out = (1-z)*tanh(xn + r*bn) -------
__global__ __launch_bounds__(256) void gru_kernel(const bf16* __restrict__ h2B,
                                                  const bf16* __restrict__ WgruB,
                                                  const float* __restrict__ bih,
                                                  const float* __restrict__ bhh,
                                                  float* __restrict__ gout) {
  const int lane = threadIdx.x & 63, wave = threadIdx.x >> 6;
  const int l15 = lane & 15, quad = lane >> 4;
  const int nb = blockIdx.x * 64 + wave * 16;
  int arow = nb + l15; if (arow >= NN) arow = NN - 1;
  s16x8 A[4];
#pragma unroll
  for (int kt = 0; kt < 4; ++kt) A[kt] = ldfrag(h2B + (size_t)arow * HIDD + kt * 32 + quad * 8);
  f32x4 acc[6];
#pragma unroll
  for (int ct = 0; ct < 6; ++ct) {
    f32x4 a = {0.f, 0.f, 0.f, 0.f};
#pragma unroll
    for (int kt = 0; kt < 4; ++kt)
      a = MFMA16(A[kt], ldfrag(WgruB + (ct * 16 + l15) * HIDD + kt * 32 + quad * 8), a);
    acc[ct] = a;
  }
#pragma unroll
  for (int u = 0; u < 2; ++u) {
    const int cu = 16 * u + l15;
    const float br = bih[cu] + bhh[cu];
    const float bz = bih[32 + cu] + bhh[32 + cu];
    const float bni = bih[64 + cu];
    const float bnh = bhh[64 + cu];
#pragma unroll
    for (int r = 0; r < 4; ++r) {
      const int node = nb + quad * 4 + r;
      if (node < NN) {
        const float rv = sigf(acc[u][r] + br);
        const float zv = sigf(acc[2 + u][r] + bz);
        const float nv = tanhf_(acc[4 + u][r] + bni + rv * bnh);
        gout[(size_t)node * GRUH + cu] = (1.f - zv) * nv;
      }
    }
  }
}

// ------- two-phase per-graph mean pool + classifier -------
#define POOL_CHUNK 512
__global__ __launch_bounds__(256) void pool_partial_kernel(const float* __restrict__ gout,
                                                           const int* __restrict__ gids,
                                                           float* __restrict__ sums,
                                                           float* __restrict__ cnts) {
  __shared__ float ls[NGRAPH * GRUH];
  __shared__ float lc[NGRAPH];
  const int tid = threadIdx.x;
  for (int i = tid; i < NGRAPH * GRUH; i += 256) ls[i] = 0.f;
  if (tid < NGRAPH) lc[tid] = 0.f;
  __syncthreads();

  const int wave = tid >> 6, lane = tid & 63;
  const int c = lane & 31, half = lane >> 5;
  const int base = blockIdx.x * POOL_CHUNK + wave * (POOL_CHUNK / 8);

  float accv = 0.f, ccnt = 0.f;
  int curg = -1;
  for (int it = 0; it < POOL_CHUNK / 16; ++it) {
    const int n = base + it * 2 + half;
    if (n < NN) {
      const int g = gids[n];
      const float v = gout[(size_t)n * GRUH + c];
      if (g != curg) {
        if (curg >= 0) {
          atomicAdd(&ls[curg * GRUH + c], accv);
          if (c == 0) atomicAdd(&lc[curg], ccnt);
        }
        curg = g; accv = 0.f; ccnt = 0.f;
      }
      accv += v; ccnt += 1.f;
    }
  }
  if (curg >= 0) {
    atomicAdd(&ls[curg * GRUH + c], accv);
    if (c == 0) atomicAdd(&lc[curg], ccnt);
  }
  __syncthreads();
  for (int i = tid; i < NGRAPH * GRUH; i += 256)
    if (ls[i] != 0.f) atomicAdd(&sums[i], ls[i]);
  if (tid < NGRAPH && lc[tid] != 0.f) atomicAdd(&cnts[tid], lc[tid]);
}

__global__ __launch_bounds__(256) void pool_final_kernel(const float* __restrict__ sums,
                                                         const float* __restrict__ cnts,
                                                         const float* __restrict__ Wcls,
                                                         const float* __restrict__ bcls,
                                                         float* __restrict__ out) {
  const int idx = blockIdx.x * blockDim.x + threadIdx.x;
  if (idx >= NGRAPH * NCLSS) return;
  const int g = idx / NCLSS, k = idx % NCLSS;
  const float inv = 1.0f / cnts[g];
  float acc = bcls[k];
#pragma unroll
  for (int cc = 0; cc < GRUH; ++cc)
    acc += sums[g * GRUH + cc] * inv * Wcls[cc * NCLSS + k];
  out[idx] = acc;
}

extern "C" void kernel_launch(void* const* d_in, const int* in_sizes, int n_in,
                              void* d_out, int out_size, void* d_ws, size_t ws_size,
                              hipStream_t stream) {
  const float* feature  = (const float*)d_in[0];
  const int*   nbr_idx  = (const int*)d_in[1];
  const int*   deg      = (const int*)d_in[2];
  const int*   gids     = (const int*)d_in[3];
  const float* lstm_Wih = (const float*)d_in[4];
  const float* lstm_Whh = (const float*)d_in[5];
  const float* lstm_bih = (const float*)d_in[6];
  const float* lstm_bhh = (const float*)d_in[7];
  const float* W_self   = (const float*)d_in[8];
  const float* W_neigh  = (const float*)d_in[9];
  const float* b_sage   = (const float*)d_in[10];
  const float* W_gc     = (const float*)d_in[11];
  const float* b_gc     = (const float*)d_in[12];
  const float* Wih_gru  = (const float*)d_in[13];
  const float* bih_gru  = (const float*)d_in[14];
  const float* bhh_gru  = (const float*)d_in[15];
  const float* W_cls    = (const float*)d_in[16];
  const float* b_cls    = (const float*)d_in[17];

  // workspace: peak ~66 MB
  char* ws = (char*)d_ws;
  bf16*  featB = (bf16*)(ws + 0);           // [NN,128] 12.8MB (dead after sage)
  bf16*  hTB   = (bf16*)(ws + 12800000);    // [NN,128] (dead after sage)
  bf16*  h1nB  = (bf16*)(ws + 25600000);    // [NN,128] (dead after agg)
  bf16*  aggB  = (bf16*)(ws + 38400000);    // [NN,128] (dead after gc)
  bf16*  h2B   = (bf16*)(ws + 51200000);    // [NN,128]
  float* gout  = (float*)(ws + 12800000);   // alias hTB (dead after sage)
  const size_t wo = 64000000;
  bf16*  WihB  = (bf16*)(ws + wo);
  bf16*  WhhB  = (bf16*)(ws + wo + 131072);
  bf16*  WsT   = (bf16*)(ws + wo + 262144);
  bf16*  WnT   = (bf16*)(ws + wo + 294912);
  bf16*  WgT   = (bf16*)(ws + wo + 327680);
  bf16*  WgruB = (bf16*)(ws + wo + 360448);
  float* biasS = (float*)(ws + wo + 385024);
  int*   perm  = (int*)(ws + 65000000);
  int*   hist  = (int*)(ws + 65400000);     // [17]
  int*   resv  = hist + 17;                 // [17]
  float* psums = (float*)(ws + 65401216);   // [50][32]
  float* pcnts = psums + NGRAPH * GRUH;     // [50]

  prep_kernel<<<3072, 256, 0, stream>>>(feature, lstm_Wih, lstm_Whh, lstm_bih, lstm_bhh,
                                        W_self, W_neigh, W_gc, Wih_gru,
                                        featB, WihB, WhhB, WsT, WnT, WgT, WgruB, biasS);
  hipMemsetAsync(hist, 0, 34 * sizeof(int), stream);
  hipMemsetAsync(psums, 0, (NGRAPH * GRUH + NGRAPH) * sizeof(float), stream);
  hist_kernel<<<196, 256, 0, stream>>>(deg, hist);
  scatter_kernel<<<196, 256, 0, stream>>>(deg, hist, resv, perm);
  lstm_kernel<<<1563, 512, 0, stream>>>(featB, WihB, WhhB, biasS, nbr_idx, deg, perm, hTB);
  sage_kernel<<<782, 256, 0, stream>>>(featB, hTB, WsT, WnT, b_sage, deg, h1nB);
  agg_kernel<<<12500, 256, 0, stream>>>(h1nB, nbr_idx, deg, aggB);
  gc_gemm_kernel<<<782, 256, 0, stream>>>(aggB, WgT, b_gc, h2B);
  gru_kernel<<<782, 256, 0, stream>>>(h2B, WgruB, bih_gru, bhh_gru, gout);
  pool_partial_kernel<<<(NN + POOL_CHUNK - 1) / POOL_CHUNK, 256, 0, stream>>>(gout, gids, psums, pcnts);
  pool_final_kernel<<<2, 256, 0, stream>>>(psums, pcnts, W_cls, b_cls, (float*)d_out);
}

// Round 9
// 429.652 us; speedup vs baseline: 1.3527x; 1.0426x over previous
//
#include <hip/hip_runtime.h>
#include <hip/hip_bf16.h>

// GCN_71451075936314 on gfx950.
// R9: (a) lstm single-barrier pipeline. R8 evidence: step = 10.2k cyc vs
//     ~4k of floors; MfmaUtil 20 + VALUBusy 37 = phase lockstep from the
//     2-barrier step. Now Hs AND Xs are double-buffered (xor-swizzled) ->
//     ONE lgkm_barrier/step; waves drift so gemm of one wave overlaps cell
//     of another (m114 co-issue). LDS: Wih minus its (gate-o, k>=64) octets
//     (2 frags -> 8 pinned VGPR) = 112KB + 4 dbuf tiles = 149.8KB. Finished
//     rows forward hprev into the next Hs buffer. No Hs zero-init needed.
//     (b) gc_gemm+gru fused (H2 transposed through LDS): saves 25.6MB HBM
//     round trip + a dispatch.

#define NN     50000
#define HIDD   128
#define MAXD   16
#define NGRAPH 50
#define NCLSS  10
#define GRUH   32

typedef __attribute__((ext_vector_type(8))) short s16x8;    // 8 bf16 (4 VGPRs)
typedef __attribute__((ext_vector_type(4))) float f32x4;
typedef __hip_bfloat16 bf16;

#define MFMA16(a,b,c)  __builtin_amdgcn_mfma_f32_16x16x32_bf16((a),(b),(c),0,0,0)

__device__ __forceinline__ float bf2f(bf16 x) { return __bfloat162float(x); }
__device__ __forceinline__ bf16  f2bf(float x) { return __float2bfloat16(x); }
__device__ __forceinline__ s16x8 ldfrag(const bf16* p) { return *(const s16x8*)p; }

__device__ __forceinline__ float sigf(float x) {
  return __builtin_amdgcn_rcpf(1.0f + __expf(-x));
}
__device__ __forceinline__ float tanhf_(float x) {
  return 1.0f - 2.0f * __builtin_amdgcn_rcpf(1.0f + __expf(2.0f * x));
}

// barrier that drains LDS ops only — global loads stay in flight
__device__ __forceinline__ void lgkm_barrier() {
  asm volatile("s_waitcnt lgkmcnt(0)\n\ts_barrier" ::: "memory");
}

// ---------------- prep: bf16 casts + weight transposes + bias fold ----------------
__global__ void prep_kernel(const float* __restrict__ feat, const float* __restrict__ Wih,
                            const float* __restrict__ Whh, const float* __restrict__ bih,
                            const float* __restrict__ bhh, const float* __restrict__ Wself,
                            const float* __restrict__ Wneigh, const float* __restrict__ Wgc,
                            const float* __restrict__ Wgru,
                            bf16* featB, bf16* WihB, bf16* WhhB, bf16* WsT, bf16* WnT,
                            bf16* WgT, bf16* WgruB, float* biasS) {
  const int nf = NN * HIDD;
  const int total = nf + 2 * 65536 + 3 * 16384 + 12288 + 512;
  int stride = gridDim.x * blockDim.x;
  for (int idx = blockIdx.x * blockDim.x + threadIdx.x; idx < total; idx += stride) {
    if (idx < nf) { featB[idx] = f2bf(feat[idx]); continue; }
    int j = idx - nf;
    if (j < 65536) { WihB[j] = f2bf(Wih[j]); continue; }
    j -= 65536;
    if (j < 65536) { WhhB[j] = f2bf(Whh[j]); continue; }
    j -= 65536;
    if (j < 16384) { int c = j >> 7, k = j & 127; WsT[j] = f2bf(Wself[k * HIDD + c]); continue; }
    j -= 16384;
    if (j < 16384) { int c = j >> 7, k = j & 127; WnT[j] = f2bf(Wneigh[k * HIDD + c]); continue; }
    j -= 16384;
    if (j < 16384) { int c = j >> 7, k = j & 127; WgT[j] = f2bf(Wgc[k * HIDD + c]); continue; }
    j -= 16384;
    if (j < 12288) { WgruB[j] = f2bf(Wgru[j]); continue; }
    j -= 12288;
    biasS[j] = bih[j] + bhh[j];
  }
}

// ---------------- counting sort by degree (DESCENDING): LDS hist ----------------
__global__ __launch_bounds__(256) void hist_kernel(const int* __restrict__ deg, int* hist) {
  __shared__ int lh[17];
  const int tid = threadIdx.x;
  if (tid < 17) lh[tid] = 0;
  __syncthreads();
  const int i = blockIdx.x * 256 + tid;
  if (i < NN) atomicAdd(&lh[deg[i]], 1);
  __syncthreads();
  if (tid < 17 && lh[tid]) atomicAdd(&hist[tid], lh[tid]);
}

__global__ __launch_bounds__(256) void scatter_kernel(const int* __restrict__ deg,
                                                      const int* __restrict__ hist,
                                                      int* __restrict__ resv,
                                                      int* __restrict__ perm) {
  __shared__ int lh[17], lbase[17], lpos[17];
  const int tid = threadIdx.x;
  if (tid < 17) { lh[tid] = 0; lpos[tid] = 0; }
  __syncthreads();
  const int i = blockIdx.x * 256 + tid;
  const int d = (i < NN) ? deg[i] : -1;
  if (d >= 0) atomicAdd(&lh[d], 1);
  __syncthreads();
  if (tid < 17) {
    int pre = 0;
    for (int k = tid + 1; k < 17; ++k) pre += hist[k];   // descending: larger degs first
    lbase[tid] = pre + (lh[tid] ? atomicAdd(&resv[tid], lh[tid]) : 0);
  }
  __syncthreads();
  if (d >= 0) {
    const int p = lbase[d] + atomicAdd(&lpos[d], 1);
    perm[p] = i;
  }
}

// ---------------- LSTM recurrence: 512 thr / 8 waves / 32 nodes ----------------
// Single barrier per step: Xs/Hs double-buffered, all xor-swizzled by octet.
// WiA = Wih k<64 (all 512 cols); WiB = Wih k>=64 (gates i,f,g only);
// gate-o k>=64 frags pinned in regs (BiR, 8 VGPR). Whh fully pinned (64 VGPR).
__global__ __launch_bounds__(512, 1) void lstm_kernel(const bf16* __restrict__ featB,
                                                      const bf16* __restrict__ WihB,
                                                      const bf16* __restrict__ WhhB,
                                                      const float* __restrict__ biasS,
                                                      const int* __restrict__ nbr_idx,
                                                      const int* __restrict__ deg,
                                                      const int* __restrict__ perm,
                                                      bf16* __restrict__ hTB) {
  __shared__ __align__(16) bf16 WiA[512 * 64];    // 64KB: k 0..63, cols 0..511
  __shared__ __align__(16) bf16 WiB[384 * 64];    // 48KB: k 64..127, cols 0..383
  __shared__ __align__(16) bf16 Xs[2][32 * 128];  // 16KB: x rows dbuf, swizzled
  __shared__ __align__(16) bf16 Hs[2][32 * 128];  // 16KB: h dbuf, swizzled
  __shared__ int nbr_s[16 * 32];                  // [t][row]
  __shared__ int nodes_s[32];
  __shared__ int degs_s[32];

  const int tid = threadIdx.x;
  const int lane = tid & 63, w = tid >> 6;        // w = h-col block
  const int l15 = lane & 15, quad = lane >> 4;
  const int base = blockIdx.x * 32;
  const int colw = w * 16 + l15;                  // this thread's h-col
  const int srow = tid >> 4, schk = tid & 15;     // x staging assignment

  if (tid < 32) {
    const int gi = base + tid;
    const int nd = (gi < NN) ? perm[gi] : -1;
    nodes_s[tid] = nd;
    degs_s[tid] = (nd >= 0) ? deg[nd] : 0;
  }
  __syncthreads();
  for (int e = tid; e < 16 * 32; e += 512) {
    const int row = e & 31, t = e >> 5;
    const int nd = nodes_s[row];
    nbr_s[t * 32 + row] = (nd >= 0) ? nbr_idx[nd * MAXD + t] : 0;
  }
  // Wih -> LDS, octet-xor-swizzled within each 64-k half (o8 ^ (col&7))
  {
    const int c = tid;
#pragma unroll
    for (int j = 0; j < 8; ++j)
      *(s16x8*)(WiA + c * 64 + ((j ^ (c & 7)) * 8)) = ldfrag(WihB + c * HIDD + j * 8);
    if (c < 384) {
#pragma unroll
      for (int j = 0; j < 8; ++j)
        *(s16x8*)(WiB + c * 64 + ((j ^ (c & 7)) * 8)) = ldfrag(WihB + c * HIDD + 64 + j * 8);
    }
  }

  // pinned register fragments: Whh all gates (64 VGPR) + Wih gate-o k>=64 (8 VGPR)
  s16x8 Bh[4][4], BiR[2];
#pragma unroll
  for (int q = 0; q < 4; ++q)
#pragma unroll
    for (int kt = 0; kt < 4; ++kt) {
      Bh[q][kt] = ldfrag(WhhB + (q * 128 + colw) * HIDD + kt * 32 + quad * 8);
      asm volatile("" : "+v"(Bh[q][kt]));
    }
#pragma unroll
  for (int kt = 2; kt < 4; ++kt) {
    BiR[kt - 2] = ldfrag(WihB + (3 * 128 + colw) * HIDD + kt * 32 + quad * 8);
    asm volatile("" : "+v"(BiR[kt - 2]));
  }
  float biasv[4];
#pragma unroll
  for (int q = 0; q < 4; ++q) biasv[q] = biasS[q * 128 + colw];

  __syncthreads();                                // tables + WiS visible
  const int maxdeg = degs_s[0];                   // descending sort -> block max

  int mydeg[2][4];
#pragma unroll
  for (int rt = 0; rt < 2; ++rt)
#pragma unroll
    for (int rr = 0; rr < 4; ++rr) mydeg[rt][rr] = degs_s[rt * 16 + quad * 4 + rr];

  // stage x for t=0 into Xs[0] (swizzled)
  {
    const int nb0 = nbr_s[0 * 32 + srow];
    *(s16x8*)(Xs[0] + srow * 128 + ((schk ^ (srow & 15)) * 8)) =
        ldfrag(featB + (size_t)nb0 * HIDD + schk * 8);
  }
  float cst[2][4] = {{0.f, 0.f, 0.f, 0.f}, {0.f, 0.f, 0.f, 0.f}};
  float hprev[2][4] = {{0.f, 0.f, 0.f, 0.f}, {0.f, 0.f, 0.f, 0.f}};
  lgkm_barrier();                                 // Xs[0] visible

  for (int t = 0; t < maxdeg; ++t) {
    const int cur = t & 1, nxt = cur ^ 1;
    // issue next step's x gather early (vmcnt-waited in cell phase, covered)
    s16x8 xstage;
    const bool do_stage = (t + 1 < maxdeg);
    if (do_stage) {
      const int nb1 = nbr_s[(t + 1) * 32 + srow];
      xstage = ldfrag(featB + (size_t)nb1 * HIDD + schk * 8);
    }

    f32x4 acc[2][4];
#pragma unroll
    for (int rt = 0; rt < 2; ++rt)
#pragma unroll
      for (int q = 0; q < 4; ++q) acc[rt][q] = (f32x4){0.f, 0.f, 0.f, 0.f};

    // x-part: gates += x_t @ Wih^T  (A from Xs[cur], B from WiA/WiB/BiR)
#pragma unroll
    for (int kt = 0; kt < 4; ++kt) {
      const int oct = kt * 4 + quad;              // octet 0..15 within 128-k row
      const int o8 = (kt & 1) * 4 + quad;         // octet 0..7 within 64-k half
      const s16x8 ax0 = ldfrag(Xs[cur] + (0 * 16 + l15) * 128 + ((oct ^ l15) * 8));
      const s16x8 ax1 = ldfrag(Xs[cur] + (1 * 16 + l15) * 128 + ((oct ^ l15) * 8));
#pragma unroll
      for (int q = 0; q < 4; ++q) {
        const int col = q * 128 + colw;
        s16x8 bi;
        if (kt < 2)      bi = ldfrag(WiA + col * 64 + ((o8 ^ (col & 7)) * 8));
        else if (q < 3)  bi = ldfrag(WiB + col * 64 + ((o8 ^ (col & 7)) * 8));
        else             bi = BiR[kt - 2];
        acc[0][q] = MFMA16(ax0, bi, acc[0][q]);
        acc[1][q] = MFMA16(ax1, bi, acc[1][q]);
      }
    }

    // h-part: gates += h_{t-1} @ Whh^T   (skip at t=0: h0 = 0)
    if (t > 0) {
#pragma unroll
      for (int rt = 0; rt < 2; ++rt)
#pragma unroll
        for (int kt = 0; kt < 4; ++kt) {
          const int m = rt * 16 + l15;
          const int oct = kt * 4 + quad;
          const s16x8 ah = ldfrag(Hs[cur] + m * 128 + ((oct ^ l15) * 8));
#pragma unroll
          for (int q = 0; q < 4; ++q)
            acc[rt][q] = MFMA16(ah, Bh[q][kt], acc[rt][q]);
        }
    }

    // elementwise cell -> write Hs[nxt] (finished rows forward hprev)
#pragma unroll
    for (int rt = 0; rt < 2; ++rt)
#pragma unroll
      for (int rr = 0; rr < 4; ++rr) {
        const int row = rt * 16 + quad * 4 + rr;
        const float g_i = acc[rt][0][rr] + biasv[0];
        const float g_f = acc[rt][1][rr] + biasv[1];
        const float g_g = acc[rt][2][rr] + biasv[2];
        const float g_o = acc[rt][3][rr] + biasv[3];
        const float iv = sigf(g_i), fv = sigf(g_f);
        const float gv = tanhf_(g_g), ov = sigf(g_o);
        const float cn = fv * cst[rt][rr] + iv * gv;
        const float hn_new = ov * tanhf_(cn);
        const bool act = (t < mydeg[rt][rr]);
        if (act) cst[rt][rr] = cn;
        const float hn = act ? hn_new : hprev[rt][rr];
        hprev[rt][rr] = hn;
        Hs[nxt][row * 128 + (((colw >> 3) ^ (row & 15)) * 8) + (colw & 7)] = f2bf(hn);
      }
    // stage next x into Xs[nxt]
    if (do_stage)
      *(s16x8*)(Xs[nxt] + srow * 128 + ((schk ^ (srow & 15)) * 8)) = xstage;

    lgkm_barrier();   // single barrier: all dbuf writes visible, reads done
  }

  // epilogue: Hs[maxdeg&1] (swizzled) -> hTB
  const bf16* Hf = Hs[maxdeg & 1];
  for (int e = tid; e < 32 * 16; e += 512) {
    const int row = e >> 4, j = e & 15;
    const int nd = nodes_s[row];
    if (nd >= 0) {
      const s16x8 v = ldfrag(Hf + row * 128 + ((j ^ (row & 15)) * 8));
      *(s16x8*)(hTB + (size_t)nd * HIDD + j * 8) = v;
    }
  }
}

// ------- SAGE: h1n = relu(feat@W_self + hT@W_neigh + b) * rsqrt(deg) -------
__global__ __launch_bounds__(256) void sage_kernel(const bf16* __restrict__ featB,
                                                   const bf16* __restrict__ hTB,
                                                   const bf16* __restrict__ WsT,
                                                   const bf16* __restrict__ WnT,
                                                   const float* __restrict__ b_sage,
                                                   const int* __restrict__ deg,
                                                   bf16* __restrict__ h1n) {
  const int lane = threadIdx.x & 63, wave = threadIdx.x >> 6;
  const int l15 = lane & 15, quad = lane >> 4;
  const int nb = blockIdx.x * 64 + wave * 16;
  int arow = nb + l15; if (arow >= NN) arow = NN - 1;
  s16x8 Fa[4], Ha[4];
#pragma unroll
  for (int kt = 0; kt < 4; ++kt) {
    Fa[kt] = ldfrag(featB + (size_t)arow * HIDD + kt * 32 + quad * 8);
    Ha[kt] = ldfrag(hTB + (size_t)arow * HIDD + kt * 32 + quad * 8);
  }
  int nodes[4]; float nrm[4];
#pragma unroll
  for (int r = 0; r < 4; ++r) {
    const int nd = nb + quad * 4 + r;
    nodes[r] = nd;
    nrm[r] = rsqrtf((float)deg[(nd < NN) ? nd : (NN - 1)]);
  }
  for (int ct = 0; ct < 8; ++ct) {
    const int col = ct * 16 + l15;
    f32x4 acc = {0.f, 0.f, 0.f, 0.f};
#pragma unroll
    for (int kt = 0; kt < 4; ++kt) {
      acc = MFMA16(Fa[kt], ldfrag(WsT + col * HIDD + kt * 32 + quad * 8), acc);
      acc = MFMA16(Ha[kt], ldfrag(WnT + col * HIDD + kt * 32 + quad * 8), acc);
    }
    const float bb = b_sage[col];
#pragma unroll
    for (int r = 0; r < 4; ++r)
      if (nodes[r] < NN) {
        const float v = fmaxf(acc[r] + bb, 0.f) * nrm[r];
        h1n[(size_t)nodes[r] * HIDD + col] = f2bf(v);
      }
  }
}

// ------- GraphConv aggregate: agg[n] = rsqrt(deg[n]) * sum_{t<deg} h1n[nbr[n,t]] -------
__global__ __launch_bounds__(256) void agg_kernel(const bf16* __restrict__ h1n,
                                                  const int* __restrict__ nbr_idx,
                                                  const int* __restrict__ deg,
                                                  bf16* __restrict__ aggB) {
  const int wave = threadIdx.x >> 6, lane = threadIdx.x & 63;
  const int node = blockIdx.x * 4 + wave;
  if (node >= NN) return;
  const int d = deg[node];
  const int idx_l = nbr_idx[node * MAXD + (lane & 15)];   // coalesced, broadcast via shfl
  const int c = lane * 2;
  float a0 = 0.f, a1 = 0.f;
  for (int t = 0; t < d; ++t) {
    const int nbr = __shfl(idx_l, t, 64);
    const __hip_bfloat162 v = *(const __hip_bfloat162*)(h1n + (size_t)nbr * HIDD + c);
    a0 += __bfloat162float(v.x);
    a1 += __bfloat162float(v.y);
  }
  const float nm = rsqrtf((float)d);
  aggB[(size_t)node * HIDD + c]     = f2bf(a0 * nm);
  aggB[(size_t)node * HIDD + c + 1] = f2bf(a1 * nm);
}

// ------- fused GraphConv GEMM + GRU: gout = gru(relu(agg @ W_gc + b_gc)) -------
__global__ __launch_bounds__(256) void gcgru_kernel(const bf16* __restrict__ aggB,
                                                    const bf16* __restrict__ WgT,
                                                    const float* __restrict__ b_gc,
                                                    const bf16* __restrict__ WgruB,
                                                    const float* __restrict__ bih,
                                                    const float* __restrict__ bhh,
                                                    float* __restrict__ gout) {
  __shared__ __align__(16) bf16 H2[64 * 136];     // h2 tile, padded pitch
  const int lane = threadIdx.x & 63, wave = threadIdx.x >> 6;
  const int l15 = lane & 15, quad = lane >> 4;
  const int nb = blockIdx.x * 64 + wave * 16;
  int arow = nb + l15; if (arow >= NN) arow = NN - 1;
  s16x8 A[4];
#pragma unroll
  for (int kt = 0; kt < 4; ++kt) A[kt] = ldfrag(aggB + (size_t)arow * HIDD + kt * 32 + quad * 8);
  // gc: h2 = relu(agg @ W_gc + b) -> LDS (C-layout -> row-major for gru A)
  for (int ct = 0; ct < 8; ++ct) {
    const int col = ct * 16 + l15;
    f32x4 acc = {0.f, 0.f, 0.f, 0.f};
#pragma unroll
    for (int kt = 0; kt < 4; ++kt)
      acc = MFMA16(A[kt], ldfrag(WgT + col * HIDD + kt * 32 + quad * 8), acc);
    const float bb = b_gc[col];
#pragma unroll
    for (int r = 0; r < 4; ++r)
      H2[(wave * 16 + quad * 4 + r) * 136 + col] = f2bf(fmaxf(acc[r] + bb, 0.f));
  }
  __syncthreads();
  // gru over rows wave*16 + l15
  s16x8 A2[4];
#pragma unroll
  for (int kt = 0; kt < 4; ++kt)
    A2[kt] = ldfrag(H2 + (wave * 16 + l15) * 136 + kt * 32 + quad * 8);
  f32x4 acc[6];
#pragma unroll
  for (int ct = 0; ct < 6; ++ct) {
    f32x4 a = {0.f, 0.f, 0.f, 0.f};
#pragma unroll
    for (int kt = 0; kt < 4; ++kt)
      a = MFMA16(A2[kt], ldfrag(WgruB + (ct * 16 + l15) * HIDD + kt * 32 + quad * 8), a);
    acc[ct] = a;
  }
#pragma unroll
  for (int u = 0; u < 2; ++u) {
    const int cu = 16 * u + l15;
    const float br = bih[cu] + bhh[cu];
    const float bz = bih[32 + cu] + bhh[32 + cu];
    const float bni = bih[64 + cu];
    const float bnh = bhh[64 + cu];
#pragma unroll
    for (int r = 0; r < 4; ++r) {
      const int node = nb + quad * 4 + r;
      if (node < NN) {
        const float rv = sigf(acc[u][r] + br);
        const float zv = sigf(acc[2 + u][r] + bz);
        const float nv = tanhf_(acc[4 + u][r] + bni + rv * bnh);
        gout[(size_t)node * GRUH + cu] = (1.f - zv) * nv;
      }
    }
  }
}

// ------- two-phase per-graph mean pool + classifier -------
#define POOL_CHUNK 512
__global__ __launch_bounds__(256) void pool_partial_kernel(const float* __restrict__ gout,
                                                           const int* __restrict__ gids,
                                                           float* __restrict__ sums,
                                                           float* __restrict__ cnts) {
  __shared__ float ls[NGRAPH * GRUH];
  __shared__ float lc[NGRAPH];
  const int tid = threadIdx.x;
  for (int i = tid; i < NGRAPH * GRUH; i += 256) ls[i] = 0.f;
  if (tid < NGRAPH) lc[tid] = 0.f;
  __syncthreads();

  const int wave = tid >> 6, lane = tid & 63;
  const int c = lane & 31, half = lane >> 5;
  const int base = blockIdx.x * POOL_CHUNK + wave * (POOL_CHUNK / 8);

  float accv = 0.f, ccnt = 0.f;
  int curg = -1;
  for (int it = 0; it < POOL_CHUNK / 16; ++it) {
    const int n = base + it * 2 + half;
    if (n < NN) {
      const int g = gids[n];
      const float v = gout[(size_t)n * GRUH + c];
      if (g != curg) {
        if (curg >= 0) {
          atomicAdd(&ls[curg * GRUH + c], accv);
          if (c == 0) atomicAdd(&lc[curg], ccnt);
        }
        curg = g; accv = 0.f; ccnt = 0.f;
      }
      accv += v; ccnt += 1.f;
    }
  }
  if (curg >= 0) {
    atomicAdd(&ls[curg * GRUH + c], accv);
    if (c == 0) atomicAdd(&lc[curg], ccnt);
  }
  __syncthreads();
  for (int i = tid; i < NGRAPH * GRUH; i += 256)
    if (ls[i] != 0.f) atomicAdd(&sums[i], ls[i]);
  if (tid < NGRAPH && lc[tid] != 0.f) atomicAdd(&cnts[tid], lc[tid]);
}

__global__ __launch_bounds__(256) void pool_final_kernel(const float* __restrict__ sums,
                                                         const float* __restrict__ cnts,
                                                         const float* __restrict__ Wcls,
                                                         const float* __restrict__ bcls,
                                                         float* __restrict__ out) {
  const int idx = blockIdx.x * blockDim.x + threadIdx.x;
  if (idx >= NGRAPH * NCLSS) return;
  const int g = idx / NCLSS, k = idx % NCLSS;
  const float inv = 1.0f / cnts[g];
  float acc = bcls[k];
#pragma unroll
  for (int cc = 0; cc < GRUH; ++cc)
    acc += sums[g * GRUH + cc] * inv * Wcls[cc * NCLSS + k];
  out[idx] = acc;
}

extern "C" void kernel_launch(void* const* d_in, const int* in_sizes, int n_in,
                              void* d_out, int out_size, void* d_ws, size_t ws_size,
                              hipStream_t stream) {
  const float* feature  = (const float*)d_in[0];
  const int*   nbr_idx  = (const int*)d_in[1];
  const int*   deg      = (const int*)d_in[2];
  const int*   gids     = (const int*)d_in[3];
  const float* lstm_Wih = (const float*)d_in[4];
  const float* lstm_Whh = (const float*)d_in[5];
  const float* lstm_bih = (const float*)d_in[6];
  const float* lstm_bhh = (const float*)d_in[7];
  const float* W_self   = (const float*)d_in[8];
  const float* W_neigh  = (const float*)d_in[9];
  const float* b_sage   = (const float*)d_in[10];
  const float* W_gc     = (const float*)d_in[11];
  const float* b_gc     = (const float*)d_in[12];
  const float* Wih_gru  = (const float*)d_in[13];
  const float* bih_gru  = (const float*)d_in[14];
  const float* bhh_gru  = (const float*)d_in[15];
  const float* W_cls    = (const float*)d_in[16];
  const float* b_cls    = (const float*)d_in[17];

  // workspace: peak ~66 MB
  char* ws = (char*)d_ws;
  bf16*  featB = (bf16*)(ws + 0);           // [NN,128] 12.8MB (dead after sage)
  bf16*  hTB   = (bf16*)(ws + 12800000);    // [NN,128] (dead after sage)
  bf16*  h1nB  = (bf16*)(ws + 25600000);    // [NN,128] (dead after agg)
  bf16*  aggB  = (bf16*)(ws + 38400000);    // [NN,128] (dead after gcgru)
  float* gout  = (float*)(ws + 12800000);   // alias hTB (dead after sage)
  const size_t wo = 64000000;
  bf16*  WihB  = (bf16*)(ws + wo);
  bf16*  WhhB  = (bf16*)(ws + wo + 131072);
  bf16*  WsT   = (bf16*)(ws + wo + 262144);
  bf16*  WnT   = (bf16*)(ws + wo + 294912);
  bf16*  WgT   = (bf16*)(ws + wo + 327680);
  bf16*  WgruB = (bf16*)(ws + wo + 360448);
  float* biasS = (float*)(ws + wo + 385024);
  int*   perm  = (int*)(ws + 65000000);
  int*   hist  = (int*)(ws + 65400000);     // [17]
  int*   resv  = hist + 17;                 // [17]
  float* psums = (float*)(ws + 65401216);   // [50][32]
  float* pcnts = psums + NGRAPH * GRUH;     // [50]

  prep_kernel<<<3072, 256, 0, stream>>>(feature, lstm_Wih, lstm_Whh, lstm_bih, lstm_bhh,
                                        W_self, W_neigh, W_gc, Wih_gru,
                                        featB, WihB, WhhB, WsT, WnT, WgT, WgruB, biasS);
  hipMemsetAsync(hist, 0, 34 * sizeof(int), stream);
  hipMemsetAsync(psums, 0, (NGRAPH * GRUH + NGRAPH) * sizeof(float), stream);
  hist_kernel<<<196, 256, 0, stream>>>(deg, hist);
  scatter_kernel<<<196, 256, 0, stream>>>(deg, hist, resv, perm);
  lstm_kernel<<<1563, 512, 0, stream>>>(featB, WihB, WhhB, biasS, nbr_idx, deg, perm, hTB);
  sage_kernel<<<782, 256, 0, stream>>>(featB, hTB, WsT, WnT, b_sage, deg, h1nB);
  agg_kernel<<<12500, 256, 0, stream>>>(h1nB, nbr_idx, deg, aggB);
  gcgru_kernel<<<782, 256, 0, stream>>>(aggB, WgT, b_gc, WgruB, bih_gru, bhh_gru, gout);
  pool_partial_kernel<<<(NN + POOL_CHUNK - 1) / POOL_CHUNK, 256, 0, stream>>>(gout, gids, psums, pcnts);
  pool_final_kernel<<<2, 256, 0, stream>>>(psums, pcnts, W_cls, b_cls, (float*)d_out);
}